// Round 1
// baseline (482.271 us; speedup 1.0000x reference)
//
#include <hip/hip_runtime.h>
#include <stdint.h>
#include <stddef.h>

// Problem constants (match reference setup_inputs)
#define B_    16
#define P_    16
#define S_    512
#define D_    256
#define DFF_  1024
#define VOCAB_ 5000
#define T_    256
#define ROWS_ 256        // B*P
#define EPS_  1e-6f

// JAX RNG scheme: 1 = jax_threefry_partitionable=True (modern default),
// 0 = legacy split-half counters. If round fails with absmax ~0.5 on output 0
// (r) flip this to 0.
#define PARTITIONABLE 1

// ---------------- threefry2x32 (JAX reference cipher) ----------------
__host__ __device__ __forceinline__ uint32_t rotl32_(uint32_t x, int d) {
  return (x << d) | (x >> (32 - d));
}

__host__ __device__ __forceinline__ void threefry2x32_(uint32_t k0, uint32_t k1,
                                                       uint32_t x0, uint32_t x1,
                                                       uint32_t& o0, uint32_t& o1) {
  uint32_t ks2 = k0 ^ k1 ^ 0x1BD11BDAu;
  x0 += k0; x1 += k1;
  // block 0: rot {13,15,26,6}, inject (k1, ks2+1)
  x0 += x1; x1 = rotl32_(x1, 13); x1 ^= x0;
  x0 += x1; x1 = rotl32_(x1, 15); x1 ^= x0;
  x0 += x1; x1 = rotl32_(x1, 26); x1 ^= x0;
  x0 += x1; x1 = rotl32_(x1,  6); x1 ^= x0;
  x0 += k1; x1 += ks2 + 1u;
  // block 1: rot {17,29,16,24}, inject (ks2, k0+2)
  x0 += x1; x1 = rotl32_(x1, 17); x1 ^= x0;
  x0 += x1; x1 = rotl32_(x1, 29); x1 ^= x0;
  x0 += x1; x1 = rotl32_(x1, 16); x1 ^= x0;
  x0 += x1; x1 = rotl32_(x1, 24); x1 ^= x0;
  x0 += ks2; x1 += k0 + 2u;
  // block 2: rot {13,15,26,6}, inject (k0, k1+3)
  x0 += x1; x1 = rotl32_(x1, 13); x1 ^= x0;
  x0 += x1; x1 = rotl32_(x1, 15); x1 ^= x0;
  x0 += x1; x1 = rotl32_(x1, 26); x1 ^= x0;
  x0 += x1; x1 = rotl32_(x1,  6); x1 ^= x0;
  x0 += k0; x1 += k1 + 3u;
  // block 3: rot {17,29,16,24}, inject (k1, ks2+4)
  x0 += x1; x1 = rotl32_(x1, 17); x1 ^= x0;
  x0 += x1; x1 = rotl32_(x1, 29); x1 ^= x0;
  x0 += x1; x1 = rotl32_(x1, 16); x1 ^= x0;
  x0 += x1; x1 = rotl32_(x1, 24); x1 ^= x0;
  x0 += k1; x1 += ks2 + 4u;
  // block 4: rot {13,15,26,6}, inject (ks2, k0+5)
  x0 += x1; x1 = rotl32_(x1, 13); x1 ^= x0;
  x0 += x1; x1 = rotl32_(x1, 15); x1 ^= x0;
  x0 += x1; x1 = rotl32_(x1, 26); x1 ^= x0;
  x0 += x1; x1 = rotl32_(x1,  6); x1 ^= x0;
  x0 += ks2; x1 += k0 + 5u;
  o0 = x0; o1 = x1;
}

__device__ __forceinline__ uint32_t jax_bits(uint32_t k0, uint32_t k1,
                                             uint32_t i, uint32_t half) {
#if PARTITIONABLE
  uint32_t o0, o1;
  threefry2x32_(k0, k1, 0u, i, o0, o1);   // counts = (hi64, lo64) = (0, i)
  return o0 ^ o1;                          // 32-bit partitionable path
#else
  uint32_t o0, o1;
  uint32_t lo = (i < half) ? i : (i - half);
  threefry2x32_(k0, k1, lo, lo + half, o0, o1);
  return (i < half) ? o0 : o1;
#endif
}

__device__ __forceinline__ float bits_to_u01(uint32_t b) {
  return __uint_as_float((b >> 9) | 0x3F800000u) - 1.0f;  // [0,1)
}

// XLA f32 ErfInv (Giles polynomial) — matches jax.lax.erf_inv lowering
__device__ __forceinline__ float erfinv32(float x) {
  float w = -log1pf(-x * x);
  float p;
  if (w < 5.0f) {
    w -= 2.5f;
    p = 2.81022636e-08f;
    p = fmaf(p, w, 3.43273939e-07f);
    p = fmaf(p, w, -3.5233877e-06f);
    p = fmaf(p, w, -4.39150654e-06f);
    p = fmaf(p, w, 0.00021858087f);
    p = fmaf(p, w, -0.00125372503f);
    p = fmaf(p, w, -0.00417768164f);
    p = fmaf(p, w, 0.246640727f);
    p = fmaf(p, w, 1.50140941f);
  } else {
    w = sqrtf(w) - 3.0f;
    p = -0.000200214257f;
    p = fmaf(p, w, 0.000100950558f);
    p = fmaf(p, w, 0.00134934322f);
    p = fmaf(p, w, -0.00367342844f);
    p = fmaf(p, w, 0.00573950773f);
    p = fmaf(p, w, -0.0076224613f);
    p = fmaf(p, w, 0.00943887047f);
    p = fmaf(p, w, 1.00167406f);
    p = fmaf(p, w, 2.83297682f);
  }
  return p * x;
}

// jax.random.normal element i of a size-2*half f32 array
__device__ __forceinline__ float jax_normal(uint32_t k0, uint32_t k1,
                                            uint32_t i, uint32_t half) {
  float u01 = bits_to_u01(jax_bits(k0, k1, i, half));
  const float lo = -0.99999994f;  // nextafter(-1, 0)
  // uniform: floats*(hi-lo)+lo with (hi-lo) f32-rounded to 2.0; no fma contraction
  float u = __fadd_rn(__fmul_rn(u01, 2.0f), lo);
  u = fmaxf(lo, u);
  return 1.41421356f * erfinv32(u);  // float32(sqrt(2))
}

// jax.random.gumbel element i
__device__ __forceinline__ float jax_gumbel(uint32_t k0, uint32_t k1,
                                            uint32_t i, uint32_t half) {
  float u01 = bits_to_u01(jax_bits(k0, k1, i, half));
  const float tiny = 1.17549435e-38f;
  float u = __fadd_rn(__fmul_rn(u01, 1.0f), tiny);  // (1-tiny) rounds to 1.0f
  u = fmaxf(tiny, u);
  return -logf(-logf(u));
}

// ---------------- block reductions (256 threads) ----------------
__device__ __forceinline__ float block_reduce_sum(float v, float* red, int tid) {
  red[tid] = v; __syncthreads();
  #pragma unroll
  for (int st = 128; st > 0; st >>= 1) {
    if (tid < st) red[tid] += red[tid + st];
    __syncthreads();
  }
  float r = red[0];
  __syncthreads();
  return r;
}
__device__ __forceinline__ float block_reduce_max(float v, float* red, int tid) {
  red[tid] = v; __syncthreads();
  #pragma unroll
  for (int st = 128; st > 0; st >>= 1) {
    if (tid < st) red[tid] = fmaxf(red[tid], red[tid + st]);
    __syncthreads();
  }
  float r = red[0];
  __syncthreads();
  return r;
}

// ---------------- kernel 1: QKV projection + noise ----------------
__global__ __launch_bounds__(256) void qkv_kernel(
    const float* __restrict__ x,
    const float* __restrict__ wq, const float* __restrict__ bq,
    const float* __restrict__ wk, const float* __restrict__ bk,
    const float* __restrict__ wv, const float* __restrict__ bv,
    const float* __restrict__ sigmas,
    float* __restrict__ q, float* __restrict__ k, float* __restrict__ v,
    float* __restrict__ noise_q_out,
    uint32_t kq0, uint32_t kq1, uint32_t kk0, uint32_t kk1,
    uint32_t kv0, uint32_t kv1) {
  __shared__ float xs[D_];
  int row = blockIdx.x, tid = threadIdx.x;
  xs[tid] = x[row * D_ + tid];
  __syncthreads();
  float aq = bq[tid], ak = bk[tid], av = bv[tid];
  #pragma unroll 4
  for (int e = 0; e < D_; e++) {
    float xe = xs[e];
    aq = fmaf(xe, wq[e * D_ + tid], aq);
    ak = fmaf(xe, wk[e * D_ + tid], ak);
    av = fmaf(xe, wv[e * D_ + tid], av);
  }
  uint32_t i = (uint32_t)row * D_ + tid;
  float s0 = sigmas[0], s1 = sigmas[1], s2 = sigmas[2];
  float qv = aq + s0 * jax_normal(kq0, kq1, i, 32768u);
  float kv = ak + s1 * jax_normal(kk0, kk1, i, 32768u);
  float vv = av + s2 * jax_normal(kv0, kv1, i, 32768u);
  q[i] = qv; k[i] = kv; v[i] = vv;
  noise_q_out[i] = qv - aq;
}

// ---------------- kernel 2: attention + out-proj + noise + LN1 ----------------
__global__ __launch_bounds__(256) void attn_kernel(
    const float* __restrict__ x,
    const float* __restrict__ Kin, const float* __restrict__ Vin,
    const float* __restrict__ qws, const float* __restrict__ kws,
    const float* __restrict__ vws,
    const float* __restrict__ wo, const float* __restrict__ bo,
    const float* __restrict__ ln1g, const float* __restrict__ ln1b,
    const float* __restrict__ sigmas,
    float* __restrict__ attn_out, float* __restrict__ noise_z_out,
    float* __restrict__ out_ln1,
    uint32_t kz0, uint32_t kz1) {
  __shared__ float qs[D_];
  __shared__ float att[T_ + 4];
  __shared__ float z0s[D_];
  __shared__ float red[256];
  int row = blockIdx.x, tid = threadIdx.x;
  qs[tid] = qws[row * D_ + tid];
  __syncthreads();

  int wid = tid >> 6, lane = tid & 63;
  float4 myq = ((const float4*)qs)[lane];
  // logits: each wave handles 4 s-values per iteration (coalesced 1KB loads)
  for (int s0 = wid * 4; s0 <= T_; s0 += 16) {
    float part[4];
    #pragma unroll
    for (int j = 0; j < 4; j++) {
      int s = s0 + j;
      part[j] = 0.f;
      if (s <= T_) {
        const float* Krow = (s == T_) ? (kws + (size_t)row * D_)
                                      : (Kin + ((size_t)row * S_ + s) * D_);
        float4 kv4 = ((const float4*)Krow)[lane];
        part[j] = myq.x * kv4.x + myq.y * kv4.y + myq.z * kv4.z + myq.w * kv4.w;
      }
    }
    #pragma unroll
    for (int j = 0; j < 4; j++) {
      int s = s0 + j;
      float r = part[j];
      #pragma unroll
      for (int off = 32; off > 0; off >>= 1) r += __shfl_xor(r, off, 64);
      if (s <= T_ && lane == 0) att[s] = r * 0.0625f;  // / sqrt(256)
    }
  }
  __syncthreads();

  // softmax over att[0..256]
  float m = att[tid];
  if (tid == 0) m = fmaxf(m, att[T_]);
  float mx = block_reduce_max(m, red, tid);
  float e_own = expf(att[tid] - mx);
  float e_extra = (tid == 0) ? expf(att[T_] - mx) : 0.f;
  float sum = block_reduce_sum(e_own + e_extra, red, tid);
  float a_own = e_own / sum;
  att[tid] = a_own;
  if (tid == 0) att[T_] = e_extra / sum;
  __syncthreads();
  attn_out[(size_t)row * (T_ + 1) + tid] = a_own;
  if (tid == 0) attn_out[(size_t)row * (T_ + 1) + T_] = att[T_];

  // z0 = attn @ Vw  (thread d accumulates over s; row T_ comes from new v)
  float acc = 0.f;
  #pragma unroll 4
  for (int s = 0; s < T_; s++)
    acc = fmaf(att[s], Vin[((size_t)row * S_ + s) * D_ + tid], acc);
  acc = fmaf(att[T_], vws[(size_t)row * D_ + tid], acc);
  z0s[tid] = acc;
  __syncthreads();

  // z_ = z0 @ wo + bo, add noise, residual + LN1
  float zp = bo[tid];
  #pragma unroll 4
  for (int e = 0; e < D_; e++) zp = fmaf(z0s[e], wo[e * D_ + tid], zp);
  uint32_t i = (uint32_t)row * D_ + tid;
  float zv = zp + sigmas[3] * jax_normal(kz0, kz1, i, 32768u);
  noise_z_out[i] = zv - zp;
  float yv = zv + x[i];

  float mu = block_reduce_sum(yv, red, tid) * (1.0f / 256.0f);
  float dv = yv - mu;
  float var = block_reduce_sum(dv * dv, red, tid) * (1.0f / 256.0f);
  out_ln1[i] = dv * rsqrtf(var + EPS_) * ln1g[tid] + ln1b[tid];
}

// ---------------- kernel 3: FFN + LN2 -> r ----------------
__global__ __launch_bounds__(256) void ff_kernel(
    const float* __restrict__ oln,
    const float* __restrict__ w1, const float* __restrict__ b1,
    const float* __restrict__ w2, const float* __restrict__ b2,
    const float* __restrict__ ln2g, const float* __restrict__ ln2b,
    float* __restrict__ r_out) {
  __shared__ float os[D_];
  __shared__ float hs[DFF_];
  __shared__ float red[256];
  int row = blockIdx.x, tid = threadIdx.x;
  os[tid] = oln[(size_t)row * D_ + tid];
  __syncthreads();
  float a0 = b1[tid], a1 = b1[tid + 256], a2 = b1[tid + 512], a3 = b1[tid + 768];
  #pragma unroll 4
  for (int e = 0; e < D_; e++) {
    float oe = os[e];
    const float* wr = w1 + (size_t)e * DFF_ + tid;
    a0 = fmaf(oe, wr[0], a0);
    a1 = fmaf(oe, wr[256], a1);
    a2 = fmaf(oe, wr[512], a2);
    a3 = fmaf(oe, wr[768], a3);
  }
  hs[tid] = fmaxf(a0, 0.f);
  hs[tid + 256] = fmaxf(a1, 0.f);
  hs[tid + 512] = fmaxf(a2, 0.f);
  hs[tid + 768] = fmaxf(a3, 0.f);
  __syncthreads();
  float f = b2[tid];
  #pragma unroll 4
  for (int e = 0; e < DFF_; e++) f = fmaf(hs[e], w2[(size_t)e * D_ + tid], f);
  float yv = f + os[tid];
  float mu = block_reduce_sum(yv, red, tid) * (1.0f / 256.0f);
  float dv = yv - mu;
  float var = block_reduce_sum(dv * dv, red, tid) * (1.0f / 256.0f);
  r_out[(size_t)row * D_ + tid] = dv * rsqrtf(var + EPS_) * ln2g[tid] + ln2b[tid];
}

// ---------------- kernel 4: preds = r @ w_out (256x5000x256) ----------------
__global__ __launch_bounds__(256) void preds_kernel(
    const float* __restrict__ r, const float* __restrict__ w_out,
    float* __restrict__ preds) {
  int tid = threadIdx.x;
  int col = blockIdx.x * 250 + tid;       // 20 col-chunks of 250
  int rb = blockIdx.y * 16;               // 16 row-chunks of 16
  if (tid >= 250) return;
  float acc[16];
  #pragma unroll
  for (int m = 0; m < 16; m++) acc[m] = 0.f;
  for (int e = 0; e < D_; e++) {
    float wv = w_out[(size_t)e * VOCAB_ + col];
    #pragma unroll
    for (int m = 0; m < 16; m++)
      acc[m] = fmaf(r[(size_t)(rb + m) * D_ + e], wv, acc[m]);  // uniform -> s_load
  }
  #pragma unroll
  for (int m = 0; m < 16; m++)
    preds[(size_t)(rb + m) * VOCAB_ + col] = acc[m];
}

// ---------------- kernel 5: softmax-pick w = probas[y] ----------------
__global__ __launch_bounds__(256) void pick_kernel(
    const float* __restrict__ preds, const int* __restrict__ y,
    float* __restrict__ w) {
  __shared__ float red[256];
  int row = blockIdx.x, tid = threadIdx.x;
  const float* pr = preds + (size_t)row * VOCAB_;
  float m = -INFINITY;
  for (int j = tid; j < VOCAB_; j += 256) m = fmaxf(m, pr[j]);
  float mx = block_reduce_max(m, red, tid);
  float s = 0.f;
  for (int j = tid; j < VOCAB_; j += 256) s += expf(pr[j] - mx);
  float sum = block_reduce_sum(s, red, tid);
  if (tid == 0) w[row] = expf(pr[y[row]] - mx) / sum;
}

// ---------------- kernel 6: w_norm + gumbel-max categorical -> i_t ----------------
__global__ __launch_bounds__(256) void cat_kernel(
    const float* __restrict__ w, int* __restrict__ i_t,
    uint32_t kc0, uint32_t kc1) {
  __shared__ float wv[256];
  __shared__ float wn[256];
  int tid = threadIdx.x;
  int b = tid >> 4;
  wv[tid] = w[tid];
  __syncthreads();
  float mx = -INFINITY;
  for (int j = 0; j < 16; j++) mx = fmaxf(mx, wv[b * 16 + j]);
  float ev = expf(wv[tid] - mx);
  wn[tid] = ev;
  __syncthreads();
  float sum = 0.f;
  for (int j = 0; j < 16; j++) sum += wn[b * 16 + j];
  __syncthreads();
  wn[tid] = ev / sum;
  __syncthreads();
  // i_t[b,p] = argmax_j( gumbel[(b,p,j)] + w_norm[b,j] ), first-max ties
  float best = -INFINITY;
  int bi = 0;
  for (int j = 0; j < 16; j++) {
    uint32_t idx = (uint32_t)tid * 16u + (uint32_t)j;
    float g = jax_gumbel(kc0, kc1, idx, 2048u);
    float sc = g + wn[b * 16 + j];
    if (sc > best) { best = sc; bi = j; }
  }
  i_t[tid] = bi;
}

// ---------------- kernel 7: resample/copy K,V,R (the big one) ----------------
__global__ __launch_bounds__(256) void resample_kernel(
    const float4* __restrict__ Kin, const float4* __restrict__ Vin,
    const float4* __restrict__ Rin,
    const float4* __restrict__ knew, const float4* __restrict__ vnew,
    const float4* __restrict__ rnew,
    const int* __restrict__ i_t,
    float4* __restrict__ Kout, float4* __restrict__ Vout,
    float4* __restrict__ Rout) {
  uint32_t idx = blockIdx.x * 256u + threadIdx.x;   // float4 index, < 2^23
  uint32_t d4 = idx & 63u;
  uint32_t s  = (idx >> 6) & 511u;
  uint32_t p  = (idx >> 15) & 15u;
  uint32_t b  = idx >> 19;
  const float4* in; const float4* nw; float4* out;
  if (blockIdx.y == 0)      { in = Kin; nw = knew; out = Kout; }
  else if (blockIdx.y == 1) { in = Vin; nw = vnew; out = Vout; }
  else                      { in = Rin; nw = rnew; out = Rout; }
  float4 val;
  if (s > T_) {
    val = in[idx];
  } else {
    uint32_t ip = (uint32_t)i_t[(b << 4) | p];
    if (s == T_) val = nw[(((b << 4) | ip) << 6) | d4];
    else         val = in[(((((b << 4) | ip) << 9) | s) << 6) | d4];
  }
  out[idx] = val;
}

// ---------------- host ----------------
static void compute_subkeys(uint32_t nk[5][2]) {
  const uint32_t k0 = 0u, k1 = 1234u;  // jax.random.key(1234)
#if PARTITIONABLE
  for (uint32_t j = 0; j < 5; j++)
    threefry2x32_(k0, k1, 0u, j, nk[j][0], nk[j][1]);
#else
  uint32_t o0[5], o1[5], out[10];
  for (uint32_t m = 0; m < 5; m++) threefry2x32_(k0, k1, m, m + 5u, o0[m], o1[m]);
  for (int m = 0; m < 5; m++) { out[m] = o0[m]; out[m + 5] = o1[m]; }
  for (int j = 0; j < 5; j++) { nk[j][0] = out[2 * j]; nk[j][1] = out[2 * j + 1]; }
#endif
}

extern "C" void kernel_launch(void* const* d_in, const int* in_sizes, int n_in,
                              void* d_out, int out_size, void* d_ws, size_t ws_size,
                              hipStream_t stream) {
  const float* x    = (const float*)d_in[0];
  const int*   y    = (const int*)d_in[1];
  const float* Kin  = (const float*)d_in[2];
  const float* Vin  = (const float*)d_in[3];
  const float* Rin  = (const float*)d_in[4];
  const float* wq   = (const float*)d_in[5];  const float* bq = (const float*)d_in[6];
  const float* wk   = (const float*)d_in[7];  const float* bk = (const float*)d_in[8];
  const float* wv   = (const float*)d_in[9];  const float* bv = (const float*)d_in[10];
  const float* wo   = (const float*)d_in[11]; const float* bo = (const float*)d_in[12];
  const float* w1   = (const float*)d_in[13]; const float* b1 = (const float*)d_in[14];
  const float* w2   = (const float*)d_in[15]; const float* b2 = (const float*)d_in[16];
  const float* ln1g = (const float*)d_in[17]; const float* ln1b = (const float*)d_in[18];
  const float* ln2g = (const float*)d_in[19]; const float* ln2b = (const float*)d_in[20];
  const float* w_out = (const float*)d_in[21];
  const float* sigmas = (const float*)d_in[22];
  (void)in_sizes; (void)n_in; (void)out_size; (void)ws_size;

  // output layout (flat f32, return order): r, attn, noise_q, noise_z, K, V, R
  float* out        = (float*)d_out;
  float* r_out      = out;
  float* attn_out   = out + 65536;
  float* noiseq_out = out + 131328;
  float* noisez_out = out + 196864;
  float* K_out      = out + 262400;
  float* V_out      = out + 33816832;
  float* R_out      = out + 67371264;

  // workspace layout (floats)
  float* wsf   = (float*)d_ws;
  float* qws   = wsf;                 // 65536
  float* kws   = wsf + 65536;         // 65536
  float* vws   = wsf + 131072;        // 65536
  float* oln   = wsf + 196608;        // 65536
  float* preds = wsf + 262144;        // 1,280,000
  float* wprob = wsf + 1542144;       // 256
  int*   i_t   = (int*)(wsf + 1542400); // 256

  uint32_t nk[5][2];
  compute_subkeys(nk);  // nk[0]=q, nk[1]=k, nk[2]=v, nk[3]=z, nk[4]=categorical

  qkv_kernel<<<ROWS_, 256, 0, stream>>>(x, wq, bq, wk, bk, wv, bv, sigmas,
      qws, kws, vws, noiseq_out,
      nk[0][0], nk[0][1], nk[1][0], nk[1][1], nk[2][0], nk[2][1]);
  attn_kernel<<<ROWS_, 256, 0, stream>>>(x, Kin, Vin, qws, kws, vws, wo, bo,
      ln1g, ln1b, sigmas, attn_out, noisez_out, oln, nk[3][0], nk[3][1]);
  ff_kernel<<<ROWS_, 256, 0, stream>>>(oln, w1, b1, w2, b2, ln2g, ln2b, r_out);
  preds_kernel<<<dim3(20, 16), 256, 0, stream>>>(r_out, w_out, preds);
  pick_kernel<<<ROWS_, 256, 0, stream>>>(preds, y, wprob);
  cat_kernel<<<1, 256, 0, stream>>>(wprob, i_t, nk[4][0], nk[4][1]);
  resample_kernel<<<dim3(32768, 3), 256, 0, stream>>>(
      (const float4*)Kin, (const float4*)Vin, (const float4*)Rin,
      (const float4*)kws, (const float4*)vws, (const float4*)r_out,
      i_t, (float4*)K_out, (float4*)V_out, (float4*)R_out);
}

// Round 2
// 271.118 us; speedup vs baseline: 1.7788x; 1.7788x over previous
//
#include <hip/hip_runtime.h>
#include <stdint.h>
#include <stddef.h>

// Problem constants (match reference setup_inputs)
#define B_    16
#define P_    16
#define S_    512
#define D_    256
#define DFF_  1024
#define VOCAB_ 5000
#define T_    256
#define ROWS_ 256        // B*P
#define EPS_  1e-6f

#define PARTITIONABLE 1  // jax_threefry_partitionable=True (verified in R1)

// ---------------- threefry2x32 (JAX reference cipher) ----------------
__host__ __device__ __forceinline__ uint32_t rotl32_(uint32_t x, int d) {
  return (x << d) | (x >> (32 - d));
}

__host__ __device__ __forceinline__ void threefry2x32_(uint32_t k0, uint32_t k1,
                                                       uint32_t x0, uint32_t x1,
                                                       uint32_t& o0, uint32_t& o1) {
  uint32_t ks2 = k0 ^ k1 ^ 0x1BD11BDAu;
  x0 += k0; x1 += k1;
  x0 += x1; x1 = rotl32_(x1, 13); x1 ^= x0;
  x0 += x1; x1 = rotl32_(x1, 15); x1 ^= x0;
  x0 += x1; x1 = rotl32_(x1, 26); x1 ^= x0;
  x0 += x1; x1 = rotl32_(x1,  6); x1 ^= x0;
  x0 += k1; x1 += ks2 + 1u;
  x0 += x1; x1 = rotl32_(x1, 17); x1 ^= x0;
  x0 += x1; x1 = rotl32_(x1, 29); x1 ^= x0;
  x0 += x1; x1 = rotl32_(x1, 16); x1 ^= x0;
  x0 += x1; x1 = rotl32_(x1, 24); x1 ^= x0;
  x0 += ks2; x1 += k0 + 2u;
  x0 += x1; x1 = rotl32_(x1, 13); x1 ^= x0;
  x0 += x1; x1 = rotl32_(x1, 15); x1 ^= x0;
  x0 += x1; x1 = rotl32_(x1, 26); x1 ^= x0;
  x0 += x1; x1 = rotl32_(x1,  6); x1 ^= x0;
  x0 += k0; x1 += k1 + 3u;
  x0 += x1; x1 = rotl32_(x1, 17); x1 ^= x0;
  x0 += x1; x1 = rotl32_(x1, 29); x1 ^= x0;
  x0 += x1; x1 = rotl32_(x1, 16); x1 ^= x0;
  x0 += x1; x1 = rotl32_(x1, 24); x1 ^= x0;
  x0 += k1; x1 += ks2 + 4u;
  x0 += x1; x1 = rotl32_(x1, 13); x1 ^= x0;
  x0 += x1; x1 = rotl32_(x1, 15); x1 ^= x0;
  x0 += x1; x1 = rotl32_(x1, 26); x1 ^= x0;
  x0 += x1; x1 = rotl32_(x1,  6); x1 ^= x0;
  x0 += ks2; x1 += k0 + 5u;
  o0 = x0; o1 = x1;
}

__device__ __forceinline__ uint32_t jax_bits(uint32_t k0, uint32_t k1,
                                             uint32_t i, uint32_t half) {
#if PARTITIONABLE
  uint32_t o0, o1;
  threefry2x32_(k0, k1, 0u, i, o0, o1);
  return o0 ^ o1;
#else
  uint32_t o0, o1;
  uint32_t lo = (i < half) ? i : (i - half);
  threefry2x32_(k0, k1, lo, lo + half, o0, o1);
  return (i < half) ? o0 : o1;
#endif
}

__device__ __forceinline__ float bits_to_u01(uint32_t b) {
  return __uint_as_float((b >> 9) | 0x3F800000u) - 1.0f;
}

// XLA f32 ErfInv (Giles polynomial)
__device__ __forceinline__ float erfinv32(float x) {
  float w = -log1pf(-x * x);
  float p;
  if (w < 5.0f) {
    w -= 2.5f;
    p = 2.81022636e-08f;
    p = fmaf(p, w, 3.43273939e-07f);
    p = fmaf(p, w, -3.5233877e-06f);
    p = fmaf(p, w, -4.39150654e-06f);
    p = fmaf(p, w, 0.00021858087f);
    p = fmaf(p, w, -0.00125372503f);
    p = fmaf(p, w, -0.00417768164f);
    p = fmaf(p, w, 0.246640727f);
    p = fmaf(p, w, 1.50140941f);
  } else {
    w = sqrtf(w) - 3.0f;
    p = -0.000200214257f;
    p = fmaf(p, w, 0.000100950558f);
    p = fmaf(p, w, 0.00134934322f);
    p = fmaf(p, w, -0.00367342844f);
    p = fmaf(p, w, 0.00573950773f);
    p = fmaf(p, w, -0.0076224613f);
    p = fmaf(p, w, 0.00943887047f);
    p = fmaf(p, w, 1.00167406f);
    p = fmaf(p, w, 2.83297682f);
  }
  return p * x;
}

__device__ __forceinline__ float jax_normal(uint32_t k0, uint32_t k1,
                                            uint32_t i, uint32_t half) {
  float u01 = bits_to_u01(jax_bits(k0, k1, i, half));
  const float lo = -0.99999994f;
  float u = __fadd_rn(__fmul_rn(u01, 2.0f), lo);
  u = fmaxf(lo, u);
  return 1.41421356f * erfinv32(u);
}

__device__ __forceinline__ float jax_gumbel(uint32_t k0, uint32_t k1,
                                            uint32_t i, uint32_t half) {
  float u01 = bits_to_u01(jax_bits(k0, k1, i, half));
  const float tiny = 1.17549435e-38f;
  float u = __fadd_rn(__fmul_rn(u01, 1.0f), tiny);
  u = fmaxf(tiny, u);
  return -logf(-logf(u));
}

// ---------------- 1024-thread block reductions (wave shfl + 16-slot LDS) ----
__device__ __forceinline__ float blk_sum(float v, float* red, int tid) {
  #pragma unroll
  for (int off = 32; off > 0; off >>= 1) v += __shfl_xor(v, off, 64);
  if ((tid & 63) == 0) red[tid >> 6] = v;
  __syncthreads();
  if (tid == 0) {
    float s = 0.f;
    #pragma unroll
    for (int i = 0; i < 16; i++) s += red[i];
    red[16] = s;
  }
  __syncthreads();
  float r = red[16];
  __syncthreads();
  return r;
}
__device__ __forceinline__ float blk_max(float v, float* red, int tid) {
  #pragma unroll
  for (int off = 32; off > 0; off >>= 1) v = fmaxf(v, __shfl_xor(v, off, 64));
  if ((tid & 63) == 0) red[tid >> 6] = v;
  __syncthreads();
  if (tid == 0) {
    float s = -INFINITY;
    #pragma unroll
    for (int i = 0; i < 16; i++) s = fmaxf(s, red[i]);
    red[16] = s;
  }
  __syncthreads();
  float r = red[16];
  __syncthreads();
  return r;
}
// 256-element reductions (only t<256 carry data; others pass identity)
__device__ __forceinline__ float block_reduce_sum256(float v, float* red, int tid) {
  return blk_sum(v, red, tid);
}

// ---------------- fused per-row kernel: qkv+noise+attn+wo+LN1+FFN+LN2 -------
// grid = 256 rows, block = 1024 threads (16 waves/CU for latency hiding)
__global__ __launch_bounds__(1024) void fused_row_kernel(
    const float* __restrict__ x,
    const float* __restrict__ Kin, const float* __restrict__ Vin,
    const float* __restrict__ wq, const float* __restrict__ bq,
    const float* __restrict__ wk, const float* __restrict__ bk,
    const float* __restrict__ wv, const float* __restrict__ bv,
    const float* __restrict__ wo, const float* __restrict__ bo,
    const float* __restrict__ w1, const float* __restrict__ b1,
    const float* __restrict__ w2, const float* __restrict__ b2,
    const float* __restrict__ ln1g, const float* __restrict__ ln1b,
    const float* __restrict__ ln2g, const float* __restrict__ ln2b,
    const float* __restrict__ sigmas,
    float* __restrict__ kws, float* __restrict__ vws,
    float* __restrict__ attn_out, float* __restrict__ noiseq_out,
    float* __restrict__ noisez_out, float* __restrict__ r_out,
    uint32_t kq0, uint32_t kq1, uint32_t kk0, uint32_t kk1,
    uint32_t kv0, uint32_t kv1, uint32_t kz0, uint32_t kz1) {
  __shared__ float xs[D_], qs[D_], ksh[D_], vsh[D_], z0s[D_], os[D_];
  __shared__ float att[T_ + 4];
  __shared__ float hs[DFF_];
  __shared__ float sc3[3][4][D_];   // split-K partials
  __shared__ float red[32];
  const int row = blockIdx.x, t = threadIdx.x;
  const int col = t & 255, ec = t >> 8;      // ec in [0,4)

  if (t < D_) xs[t] = x[row * D_ + t];
  __syncthreads();

  // ---- QKV: each quarter-thread-group accumulates a 64-long K-slice ----
  {
    float aq = 0.f, ak = 0.f, av = 0.f;
    const int e0 = ec * 64;
    #pragma unroll 8
    for (int e = e0; e < e0 + 64; e++) {
      float xe = xs[e];
      aq = fmaf(xe, wq[e * D_ + col], aq);
      ak = fmaf(xe, wk[e * D_ + col], ak);
      av = fmaf(xe, wv[e * D_ + col], av);
    }
    sc3[0][ec][col] = aq; sc3[1][ec][col] = ak; sc3[2][ec][col] = av;
  }
  __syncthreads();
  if (t < D_) {
    float qf = bq[t] + sc3[0][0][t] + sc3[0][1][t] + sc3[0][2][t] + sc3[0][3][t];
    float kf = bk[t] + sc3[1][0][t] + sc3[1][1][t] + sc3[1][2][t] + sc3[1][3][t];
    float vf = bv[t] + sc3[2][0][t] + sc3[2][1][t] + sc3[2][2][t] + sc3[2][3][t];
    uint32_t i = (uint32_t)row * D_ + t;
    float qn = qf + sigmas[0] * jax_normal(kq0, kq1, i, 32768u);
    float kn = kf + sigmas[1] * jax_normal(kk0, kk1, i, 32768u);
    float vn = vf + sigmas[2] * jax_normal(kv0, kv1, i, 32768u);
    qs[t] = qn; ksh[t] = kn; vsh[t] = vn;
    kws[i] = kn; vws[i] = vn;
    noiseq_out[i] = qn - qf;
  }
  __syncthreads();

  // ---- logits: 16 waves, 4 s-values per wave per round, float4 dot ----
  {
    const int wid = t >> 6, lane = t & 63;
    float4 myq = ((const float4*)qs)[lane];
    for (int s0 = wid * 4; s0 <= T_; s0 += 64) {
      #pragma unroll
      for (int j = 0; j < 4; j++) {
        int s = s0 + j;
        if (s <= T_) {
          const float* Krow = (s == T_) ? ksh
                                        : (Kin + ((size_t)row * S_ + s) * D_);
          float4 k4 = ((const float4*)Krow)[lane];
          float rr = myq.x * k4.x + myq.y * k4.y + myq.z * k4.z + myq.w * k4.w;
          #pragma unroll
          for (int off = 32; off > 0; off >>= 1) rr += __shfl_xor(rr, off, 64);
          if (lane == 0) att[s] = rr * 0.0625f;   // / sqrt(256)
        }
      }
    }
  }
  __syncthreads();

  // ---- softmax over 257 logits ----
  {
    float v = (t <= T_) ? att[t] : -INFINITY;
    float mx = blk_max(v, red, t);
    float e = (t <= T_) ? expf(att[t] - mx) : 0.f;
    float sum = blk_sum(e, red, t);
    if (t <= T_) {
      float a = e / sum;
      att[t] = a;
      attn_out[(size_t)row * (T_ + 1) + t] = a;
    }
  }
  __syncthreads();

  // ---- z0 = attn @ Vw (split s-range across ec) ----
  {
    float acc = 0.f;
    const int s0 = ec * 64;
    #pragma unroll 8
    for (int s = s0; s < s0 + 64; s++)
      acc = fmaf(att[s], Vin[((size_t)row * S_ + s) * D_ + col], acc);
    if (ec == 3) acc = fmaf(att[T_], vsh[col], acc);
    sc3[0][ec][col] = acc;
  }
  __syncthreads();
  if (t < D_) z0s[t] = sc3[0][0][t] + sc3[0][1][t] + sc3[0][2][t] + sc3[0][3][t];
  __syncthreads();

  // ---- z = z0 @ wo + bo + noise; y = z + x; LN1 ----
  {
    float acc = 0.f;
    const int e0 = ec * 64;
    #pragma unroll 8
    for (int e = e0; e < e0 + 64; e++)
      acc = fmaf(z0s[e], wo[e * D_ + col], acc);
    sc3[0][ec][col] = acc;
  }
  __syncthreads();
  if (t < D_) {
    float zp = bo[t] + sc3[0][0][t] + sc3[0][1][t] + sc3[0][2][t] + sc3[0][3][t];
    uint32_t i = (uint32_t)row * D_ + t;
    float zn = zp + sigmas[3] * jax_normal(kz0, kz1, i, 32768u);
    noisez_out[i] = zn - zp;
    z0s[t] = zn + xs[t];     // reuse z0s as y
  }
  __syncthreads();
  {
    float y = (t < D_) ? z0s[t] : 0.f;
    float mu = blk_sum(y, red, t) * (1.0f / 256.0f);
    float dv = (t < D_) ? (z0s[t] - mu) : 0.f;
    float var = blk_sum(dv * dv, red, t) * (1.0f / 256.0f);
    if (t < D_) os[t] = dv * rsqrtf(var + EPS_) * ln1g[t] + ln1b[t];
  }
  __syncthreads();

  // ---- FFN layer 1: all 1024 threads, one DFF output each ----
  {
    float acc = b1[t];
    #pragma unroll 8
    for (int e = 0; e < D_; e++) acc = fmaf(os[e], w1[(size_t)e * DFF_ + t], acc);
    hs[t] = fmaxf(acc, 0.f);
  }
  __syncthreads();

  // ---- FFN layer 2: split 1024-long K across ec ----
  {
    float acc = 0.f;
    const int e0 = ec * 256;
    #pragma unroll 8
    for (int e = e0; e < e0 + 256; e++)
      acc = fmaf(hs[e], w2[(size_t)e * D_ + col], acc);
    sc3[0][ec][col] = acc;
  }
  __syncthreads();
  if (t < D_) {
    float f = b2[t] + sc3[0][0][t] + sc3[0][1][t] + sc3[0][2][t] + sc3[0][3][t];
    z0s[t] = f + os[t];
  }
  __syncthreads();
  {
    float y = (t < D_) ? z0s[t] : 0.f;
    float mu = blk_sum(y, red, t) * (1.0f / 256.0f);
    float dv = (t < D_) ? (z0s[t] - mu) : 0.f;
    float var = blk_sum(dv * dv, red, t) * (1.0f / 256.0f);
    if (t < D_)
      r_out[(size_t)row * D_ + t] = dv * rsqrtf(var + EPS_) * ln2g[t] + ln2b[t];
  }
}

// ---------------- preds = r @ w_out (256x5000x256) ----------------
__global__ __launch_bounds__(256) void preds_kernel(
    const float* __restrict__ r, const float* __restrict__ w_out,
    float* __restrict__ preds) {
  int tid = threadIdx.x;
  int col = blockIdx.x * 250 + tid;
  int rb = blockIdx.y * 16;
  if (tid >= 250) return;
  float acc[16];
  #pragma unroll
  for (int m = 0; m < 16; m++) acc[m] = 0.f;
  #pragma unroll 4
  for (int e = 0; e < D_; e++) {
    float wv = w_out[(size_t)e * VOCAB_ + col];
    #pragma unroll
    for (int m = 0; m < 16; m++)
      acc[m] = fmaf(r[(size_t)(rb + m) * D_ + e], wv, acc[m]);
  }
  #pragma unroll
  for (int m = 0; m < 16; m++)
    preds[(size_t)(rb + m) * VOCAB_ + col] = acc[m];
}

// ---------------- softmax-pick w = probas[y] ----------------
__device__ __forceinline__ float red256_sum(float v, float* red, int tid) {
  red[tid] = v; __syncthreads();
  #pragma unroll
  for (int st = 128; st > 0; st >>= 1) {
    if (tid < st) red[tid] += red[tid + st];
    __syncthreads();
  }
  float r = red[0]; __syncthreads();
  return r;
}
__device__ __forceinline__ float red256_max(float v, float* red, int tid) {
  red[tid] = v; __syncthreads();
  #pragma unroll
  for (int st = 128; st > 0; st >>= 1) {
    if (tid < st) red[tid] = fmaxf(red[tid], red[tid + st]);
    __syncthreads();
  }
  float r = red[0]; __syncthreads();
  return r;
}

__global__ __launch_bounds__(256) void pick_kernel(
    const float* __restrict__ preds, const int* __restrict__ y,
    float* __restrict__ w) {
  __shared__ float red[256];
  int row = blockIdx.x, tid = threadIdx.x;
  const float* pr = preds + (size_t)row * VOCAB_;
  float m = -INFINITY;
  for (int j = tid; j < VOCAB_; j += 256) m = fmaxf(m, pr[j]);
  float mx = red256_max(m, red, tid);
  float s = 0.f;
  for (int j = tid; j < VOCAB_; j += 256) s += expf(pr[j] - mx);
  float sum = red256_sum(s, red, tid);
  if (tid == 0) w[row] = expf(pr[y[row]] - mx) / sum;
}

// ---------------- w_norm + gumbel-max categorical -> i_t ----------------
__global__ __launch_bounds__(256) void cat_kernel(
    const float* __restrict__ w, int* __restrict__ i_t,
    uint32_t kc0, uint32_t kc1) {
  __shared__ float wv[256];
  __shared__ float wn[256];
  int tid = threadIdx.x;
  int b = tid >> 4;
  wv[tid] = w[tid];
  __syncthreads();
  float mx = -INFINITY;
  for (int j = 0; j < 16; j++) mx = fmaxf(mx, wv[b * 16 + j]);
  float ev = expf(wv[tid] - mx);
  wn[tid] = ev;
  __syncthreads();
  float sum = 0.f;
  for (int j = 0; j < 16; j++) sum += wn[b * 16 + j];
  __syncthreads();
  wn[tid] = ev / sum;
  __syncthreads();
  float best = -INFINITY;
  int bi = 0;
  for (int j = 0; j < 16; j++) {
    uint32_t idx = (uint32_t)tid * 16u + (uint32_t)j;
    float g = jax_gumbel(kc0, kc1, idx, 2048u);
    float sc = g + wn[b * 16 + j];
    if (sc > best) { best = sc; bi = j; }
  }
  i_t[tid] = bi;
}

// ---------------- resample/copy K,V,R (the big one) ----------------
__global__ __launch_bounds__(256) void resample_kernel(
    const float4* __restrict__ Kin, const float4* __restrict__ Vin,
    const float4* __restrict__ Rin,
    const float4* __restrict__ knew, const float4* __restrict__ vnew,
    const float4* __restrict__ rnew,
    const int* __restrict__ i_t,
    float4* __restrict__ Kout, float4* __restrict__ Vout,
    float4* __restrict__ Rout) {
  uint32_t idx = blockIdx.x * 256u + threadIdx.x;
  uint32_t d4 = idx & 63u;
  uint32_t s  = (idx >> 6) & 511u;
  uint32_t p  = (idx >> 15) & 15u;
  uint32_t b  = idx >> 19;
  const float4* in; const float4* nw; float4* out;
  if (blockIdx.y == 0)      { in = Kin; nw = knew; out = Kout; }
  else if (blockIdx.y == 1) { in = Vin; nw = vnew; out = Vout; }
  else                      { in = Rin; nw = rnew; out = Rout; }
  float4 val;
  if (s > T_) {
    val = in[idx];
  } else {
    uint32_t ip = (uint32_t)i_t[(b << 4) | p];
    if (s == T_) val = nw[(((b << 4) | ip) << 6) | d4];
    else         val = in[(((((b << 4) | ip) << 9) | s) << 6) | d4];
  }
  out[idx] = val;
}

// ---------------- host ----------------
static void compute_subkeys(uint32_t nk[5][2]) {
  const uint32_t k0 = 0u, k1 = 1234u;
#if PARTITIONABLE
  for (uint32_t j = 0; j < 5; j++)
    threefry2x32_(k0, k1, 0u, j, nk[j][0], nk[j][1]);
#else
  uint32_t o0[5], o1[5], out[10];
  for (uint32_t m = 0; m < 5; m++) threefry2x32_(k0, k1, m, m + 5u, o0[m], o1[m]);
  for (int m = 0; m < 5; m++) { out[m] = o0[m]; out[m + 5] = o1[m]; }
  for (int j = 0; j < 5; j++) { nk[j][0] = out[2 * j]; nk[j][1] = out[2 * j + 1]; }
#endif
}

extern "C" void kernel_launch(void* const* d_in, const int* in_sizes, int n_in,
                              void* d_out, int out_size, void* d_ws, size_t ws_size,
                              hipStream_t stream) {
  const float* x    = (const float*)d_in[0];
  const int*   y    = (const int*)d_in[1];
  const float* Kin  = (const float*)d_in[2];
  const float* Vin  = (const float*)d_in[3];
  const float* Rin  = (const float*)d_in[4];
  const float* wq   = (const float*)d_in[5];  const float* bq = (const float*)d_in[6];
  const float* wk   = (const float*)d_in[7];  const float* bk = (const float*)d_in[8];
  const float* wv   = (const float*)d_in[9];  const float* bv = (const float*)d_in[10];
  const float* wo   = (const float*)d_in[11]; const float* bo = (const float*)d_in[12];
  const float* w1   = (const float*)d_in[13]; const float* b1 = (const float*)d_in[14];
  const float* w2   = (const float*)d_in[15]; const float* b2 = (const float*)d_in[16];
  const float* ln1g = (const float*)d_in[17]; const float* ln1b = (const float*)d_in[18];
  const float* ln2g = (const float*)d_in[19]; const float* ln2b = (const float*)d_in[20];
  const float* w_out = (const float*)d_in[21];
  const float* sigmas = (const float*)d_in[22];
  (void)in_sizes; (void)n_in; (void)out_size; (void)ws_size;

  // output layout (flat f32, return order): r, attn, noise_q, noise_z, K, V, R
  float* out        = (float*)d_out;
  float* r_out      = out;
  float* attn_out   = out + 65536;
  float* noiseq_out = out + 131328;
  float* noisez_out = out + 196864;
  float* K_out      = out + 262400;
  float* V_out      = out + 33816832;
  float* R_out      = out + 67371264;

  // workspace layout (floats)
  float* wsf   = (float*)d_ws;
  float* kws   = wsf;                  // 65536
  float* vws   = wsf + 65536;          // 65536
  float* preds = wsf + 131072;         // 1,280,000
  float* wprob = wsf + 1411072;        // 256
  int*   i_t   = (int*)(wsf + 1411328);

  uint32_t nk[5][2];
  compute_subkeys(nk);  // 0=q, 1=k, 2=v, 3=z, 4=categorical

  fused_row_kernel<<<ROWS_, 1024, 0, stream>>>(
      x, Kin, Vin, wq, bq, wk, bk, wv, bv, wo, bo, w1, b1, w2, b2,
      ln1g, ln1b, ln2g, ln2b, sigmas,
      kws, vws, attn_out, noiseq_out, noisez_out, r_out,
      nk[0][0], nk[0][1], nk[1][0], nk[1][1], nk[2][0], nk[2][1],
      nk[3][0], nk[3][1]);
  preds_kernel<<<dim3(20, 16), 256, 0, stream>>>(r_out, w_out, preds);
  pick_kernel<<<ROWS_, 256, 0, stream>>>(preds, y, wprob);
  cat_kernel<<<1, 256, 0, stream>>>(wprob, i_t, nk[4][0], nk[4][1]);
  resample_kernel<<<dim3(32768, 3), 256, 0, stream>>>(
      (const float4*)Kin, (const float4*)Vin, (const float4*)Rin,
      (const float4*)kws, (const float4*)vws, (const float4*)r_out,
      i_t, (float4*)K_out, (float4*)V_out, (float4*)R_out);
}